// Round 3
// baseline (3265.587 us; speedup 1.0000x reference)
//
#include <hip/hip_runtime.h>
#include <cstddef>

#define NB   256   // batch
#define TT   300   // timesteps
#define SS   150   // input feature dim
#define HH   100   // hidden
#define G4   400   // 4*H gates
#define NCLS 60

__device__ __forceinline__ float sigf(float x) {
    float e = __expf(-x);
    return 1.f / (1.f + e);
}
__device__ __forceinline__ float tanh_fast(float x) {
    float e = __expf(2.f * x);
    return 1.f - 2.f / (e + 1.f);
}

// ---------------------------------------------------------------------------
// GEMM: C[M x 400] = A[M x K] * W[400 x K]^T + (bih + bhh)
// BM=64, BN=64 tile, full K staged in LDS (k-major), 256 threads, 4x4 micro.
// grid = (M/64, 7) ; last n-tile masked (400 = 6*64 + 16).
// ---------------------------------------------------------------------------
template<int K>
__global__ __launch_bounds__(256, 2) void gemm_inproj(
    const float* __restrict__ A, const float* __restrict__ W,
    const float* __restrict__ bih, const float* __restrict__ bhh,
    float* __restrict__ C)
{
    __shared__ float As[K][64];
    __shared__ float Bs[K][64];
    const int m0 = blockIdx.x * 64;
    const int n0 = blockIdx.y * 64;
    const int tid = threadIdx.x;
    const int r = tid & 63;          // lane-major row: LDS writes conflict-free
    constexpr int K2 = K / 2;

    for (int i = tid; i < 64 * K2; i += 256) {
        int c2 = i >> 6;
        float2 v = *(const float2*)(A + (size_t)(m0 + r) * K + 2 * c2);
        As[2 * c2][r] = v.x;
        As[2 * c2 + 1][r] = v.y;
    }
    {
        int g = n0 + r;
        if (g < G4) {
            for (int i = tid; i < 64 * K2; i += 256) {
                int c2 = i >> 6;
                float2 v = *(const float2*)(W + (size_t)g * K + 2 * c2);
                Bs[2 * c2][r] = v.x;
                Bs[2 * c2 + 1][r] = v.y;
            }
        } else {
            for (int i = tid; i < 64 * K2; i += 256) {
                int c2 = i >> 6;
                Bs[2 * c2][r] = 0.f;
                Bs[2 * c2 + 1][r] = 0.f;
            }
        }
    }
    __syncthreads();

    const int tx = tid & 15, ty = tid >> 4;
    float acc[4][4] = {};
#pragma unroll 10
    for (int k = 0; k < K; ++k) {
        float4 a = *(const float4*)&As[k][ty * 4];
        float4 b = *(const float4*)&Bs[k][tx * 4];
        acc[0][0] += a.x * b.x; acc[0][1] += a.x * b.y; acc[0][2] += a.x * b.z; acc[0][3] += a.x * b.w;
        acc[1][0] += a.y * b.x; acc[1][1] += a.y * b.y; acc[1][2] += a.y * b.z; acc[1][3] += a.y * b.w;
        acc[2][0] += a.z * b.x; acc[2][1] += a.z * b.y; acc[2][2] += a.z * b.z; acc[2][3] += a.z * b.w;
        acc[3][0] += a.w * b.x; acc[3][1] += a.w * b.y; acc[3][2] += a.w * b.z; acc[3][3] += a.w * b.w;
    }

    const int g0 = n0 + tx * 4;
    if (g0 + 3 < G4) {
        float b0 = bih[g0] + bhh[g0];
        float b1 = bih[g0 + 1] + bhh[g0 + 1];
        float b2 = bih[g0 + 2] + bhh[g0 + 2];
        float b3 = bih[g0 + 3] + bhh[g0 + 3];
#pragma unroll
        for (int i = 0; i < 4; ++i) {
            float4 o;
            o.x = acc[i][0] + b0; o.y = acc[i][1] + b1;
            o.z = acc[i][2] + b2; o.w = acc[i][3] + b3;
            *(float4*)(C + (size_t)(m0 + ty * 4 + i) * G4 + g0) = o;
        }
    }
}

// ---------------------------------------------------------------------------
// LSTM recurrence. One block per sequence. 512 threads.
// MODE 0: rot+tr fused (grid 512; blocks>=256 do tr). Per-step fc(H->3) out.
// MODE 1: main layer, writes full h sequence.
// MODE 2: last main layer, accumulates mean(h), fc(H->60) + softmax -> out.
// Thread g<400 holds Whh row g in 100 VGPRs; h broadcast via LDS.
// The asm "+v" pin below makes the loaded weights opaque defs so the
// scheduler CANNOT sink the loads back into the t-loop (rounds 1-2 showed
// it re-loads Whh from global every step to hit 84 VGPRs / max occupancy).
// ---------------------------------------------------------------------------
template<int MODE>
__global__ __launch_bounds__(512, 1) void lstm_rec(
    const float* __restrict__ xgA, const float* __restrict__ xgB,
    const float* __restrict__ WhhA, const float* __restrict__ WhhB,
    const float* __restrict__ fwA, const float* __restrict__ fbA,
    const float* __restrict__ fwB, const float* __restrict__ fbB,
    float* __restrict__ oA, float* __restrict__ oB)
{
    constexpr int FSZ = (MODE == 2) ? (NCLS * HH + NCLS) : (3 * HH + 4);
    __shared__ float h_lds[HH];
    __shared__ float gate_lds[G4];
    __shared__ float fcw[FSZ];

    const int tid = threadIdx.x;
    int n = blockIdx.x;
    const float* xg = xgA;
    const float* whh = WhhA;
    const float* fw = fwA;
    const float* fb = fbA;
    float* op = oA;
    if (MODE == 0 && blockIdx.x >= NB) {
        n = blockIdx.x - NB;
        xg = xgB; whh = WhhB; fw = fwB; fb = fbB; op = oB;
    }

    float4 w[25];
    if (tid < G4) {
        const float4* wr = (const float4*)(whh + (size_t)tid * HH);
#pragma unroll
        for (int i = 0; i < 25; ++i) w[i] = wr[i];
#pragma unroll
        for (int i = 0; i < 25; ++i) {
            asm volatile("" : "+v"(w[i].x), "+v"(w[i].y), "+v"(w[i].z), "+v"(w[i].w));
        }
    }
    if (tid < HH) h_lds[tid] = 0.f;
    if (MODE == 0) {
        for (int i = tid; i < 3 * HH; i += 512) fcw[i] = fw[i];
        if (tid < 3) fcw[3 * HH + tid] = fb[tid];
    }
    if (MODE == 2) {
        for (int i = tid; i < NCLS * HH; i += 512) fcw[i] = fw[i];
        if (tid < NCLS) fcw[NCLS * HH + tid] = fb[tid];
    }
    float c = 0.f, hsum = 0.f;
    __syncthreads();

    const float* xgn = xg + (size_t)n * TT * G4 + tid;
    float x0 = 0.f, x1 = 0.f;
    if (tid < G4) { x0 = xgn[0]; x1 = xgn[G4]; }

    for (int t = 0; t < TT; ++t) {
        float acc = x0;
        x0 = x1;
        if (tid < G4 && t + 2 < TT) x1 = xgn[(size_t)(t + 2) * G4];

        if (tid < G4) {
            const float4* h4 = (const float4*)h_lds;
            float a0 = 0.f, a1 = 0.f, a2 = 0.f, a3 = 0.f;
#pragma unroll
            for (int i = 0; i < 24; i += 4) {
                float4 p = h4[i], q = h4[i + 1], s = h4[i + 2], u = h4[i + 3];
                a0 += p.x * w[i].x + p.y * w[i].y + p.z * w[i].z + p.w * w[i].w;
                a1 += q.x * w[i + 1].x + q.y * w[i + 1].y + q.z * w[i + 1].z + q.w * w[i + 1].w;
                a2 += s.x * w[i + 2].x + s.y * w[i + 2].y + s.z * w[i + 2].z + s.w * w[i + 2].w;
                a3 += u.x * w[i + 3].x + u.y * w[i + 3].y + u.z * w[i + 3].z + u.w * w[i + 3].w;
            }
            float4 p = h4[24];
            a0 += p.x * w[24].x + p.y * w[24].y + p.z * w[24].z + p.w * w[24].w;
            acc += (a0 + a1) + (a2 + a3);
            gate_lds[tid] = acc;
        }
        __syncthreads();
        if (tid < HH) {
            float ig = sigf(gate_lds[tid]);
            float fg = sigf(gate_lds[tid + HH]);
            float gg = tanh_fast(gate_lds[tid + 2 * HH]);
            float og = sigf(gate_lds[tid + 3 * HH]);
            c = fg * c + ig * gg;
            float h = og * tanh_fast(c);
            h_lds[tid] = h;
            if (MODE == 1) op[((size_t)n * TT + t) * HH + tid] = h;
            if (MODE == 2) hsum += h;
        }
        __syncthreads();
        if (MODE == 0 && tid < 64) {
            // wave0 computes the 3-wide fc of h_t; safe vs next-step h write
            // (writers can only pass the next barrier after wave0 arrives).
            float p0 = 0.f, p1 = 0.f, p2 = 0.f;
            for (int k = tid; k < HH; k += 64) {
                float hk = h_lds[k];
                p0 += hk * fcw[k];
                p1 += hk * fcw[HH + k];
                p2 += hk * fcw[2 * HH + k];
            }
#pragma unroll
            for (int s = 32; s; s >>= 1) {
                p0 += __shfl_xor(p0, s);
                p1 += __shfl_xor(p1, s);
                p2 += __shfl_xor(p2, s);
            }
            if (tid == 0) {
                size_t o = ((size_t)n * TT + t) * 3;
                op[o] = p0 + fcw[3 * HH];
                op[o + 1] = p1 + fcw[3 * HH + 1];
                op[o + 2] = p2 + fcw[3 * HH + 2];
            }
        }
    }

    if (MODE == 2) {
        if (tid < HH) h_lds[tid] = hsum * (1.f / TT);
        __syncthreads();
        if (tid < 64) {
            float logit = -3.0e38f;
            if (tid < NCLS) {
                float a = fcw[NCLS * HH + tid];
#pragma unroll
                for (int k = 0; k < HH; ++k) a += h_lds[k] * fcw[tid * HH + k];
                logit = a;
            }
            float mx = logit;
#pragma unroll
            for (int s = 32; s; s >>= 1) mx = fmaxf(mx, __shfl_xor(mx, s));
            float e = (tid < NCLS) ? __expf(logit - mx) : 0.f;
            float sum = e;
#pragma unroll
            for (int s = 32; s; s >>= 1) sum += __shfl_xor(sum, s);
            if (tid < NCLS) op[(size_t)n * NCLS + tid] = e / sum;
        }
    }
}

// ---------------------------------------------------------------------------
// Rotation/translation transform: xr = R(rot) * (x.reshape(50,3) - tr)
// One wave per (n,t); lanes 0..49 handle one point each.
// ---------------------------------------------------------------------------
__global__ __launch_bounds__(256) void transform_pts(
    const float* __restrict__ x, const float* __restrict__ rot,
    const float* __restrict__ tr, float* __restrict__ xr)
{
    const int idx = blockIdx.x * 4 + (threadIdx.x >> 6);
    const int lane = threadIdx.x & 63;
    const float* ang = rot + (size_t)idx * 3;
    float a = ang[0], b = ang[1], cg = ang[2];
    float ca = cosf(a), sa = sinf(a);
    float cb = cosf(b), sb = sinf(b);
    float cc = cosf(cg), sc = sinf(cg);
    // R = Rz @ Ry @ Rx with the reference's sign placements
    float R00 = cc * cb, R01 = cc * sb * sa + sc * ca, R02 = -cc * sb * ca + sc * sa;
    float R10 = -sc * cb, R11 = -sc * sb * sa + cc * ca, R12 = sc * sb * ca + cc * sa;
    float R20 = sb, R21 = -cb * sa, R22 = cb * ca;
    float t0 = tr[(size_t)idx * 3], t1 = tr[(size_t)idx * 3 + 1], t2 = tr[(size_t)idx * 3 + 2];
    if (lane < 50) {
        const float* xp = x + (size_t)idx * SS + lane * 3;
        float p0 = xp[0] - t0, p1 = xp[1] - t1, p2 = xp[2] - t2;
        float* o = xr + (size_t)idx * SS + lane * 3;
        o[0] = R00 * p0 + R01 * p1 + R02 * p2;
        o[1] = R10 * p0 + R11 * p1 + R12 * p2;
        o[2] = R20 * p0 + R21 * p1 + R22 * p2;
    }
}

// ---------------------------------------------------------------------------
extern "C" void kernel_launch(void* const* d_in, const int* in_sizes, int n_in,
                              void* d_out, int out_size, void* d_ws, size_t ws_size,
                              hipStream_t stream)
{
    const float* x       = (const float*)d_in[0];
    const float* rot_Wih = (const float*)d_in[1];
    const float* rot_Whh = (const float*)d_in[2];
    const float* rot_bih = (const float*)d_in[3];
    const float* rot_bhh = (const float*)d_in[4];
    const float* tr_Wih  = (const float*)d_in[5];
    const float* tr_Whh  = (const float*)d_in[6];
    const float* tr_bih  = (const float*)d_in[7];
    const float* tr_bhh  = (const float*)d_in[8];
    const float* rot_fcW = (const float*)d_in[9];
    const float* rot_fcb = (const float*)d_in[10];
    const float* tr_fcW  = (const float*)d_in[11];
    const float* tr_fcb  = (const float*)d_in[12];
    const float* W0 = (const float*)d_in[13];
    const float* U0 = (const float*)d_in[14];
    const float* b0i = (const float*)d_in[15];
    const float* b0h = (const float*)d_in[16];
    const float* W1 = (const float*)d_in[17];
    const float* U1 = (const float*)d_in[18];
    const float* b1i = (const float*)d_in[19];
    const float* b1h = (const float*)d_in[20];
    const float* W2 = (const float*)d_in[21];
    const float* U2 = (const float*)d_in[22];
    const float* b2i = (const float*)d_in[23];
    const float* b2h = (const float*)d_in[24];
    const float* fcW = (const float*)d_in[25];
    const float* fcb = (const float*)d_in[26];
    float* out = (float*)d_out;

    float* ws = (float*)d_ws;
    // layout (floats): xgA[30.72M] xgB[30.72M] rotA[230400] trO[230400]
    float* xgA  = ws;
    float* xgB  = ws + 30720000ull;
    float* rotA = ws + 61440000ull;
    float* trO  = ws + 61670400ull;
    // aliases inside xgA once its xg content is dead:
    float* xr = xgA;                    // [0, 11.52M)
    float* h0 = xgA + 11520000ull;      // [11.52M, 19.2M)
    float* h1 = xgA + 19200000ull;      // [19.2M, 26.88M)

    dim3 gg(1200, 7), bb(256);
    // 1-2: input projections for rot / tr
    gemm_inproj<150><<<gg, bb, 0, stream>>>(x, rot_Wih, rot_bih, rot_bhh, xgA);
    gemm_inproj<150><<<gg, bb, 0, stream>>>(x, tr_Wih, tr_bih, tr_bhh, xgB);
    // 3: rot + tr recurrences (fused, 512 blocks) -> angles / translations
    lstm_rec<0><<<512, 512, 0, stream>>>(xgA, xgB, rot_Whh, tr_Whh,
                                         rot_fcW, rot_fcb, tr_fcW, tr_fcb,
                                         rotA, trO);
    // 4: rotate/translate points
    transform_pts<<<19200, 256, 0, stream>>>(x, rotA, trO, xr);
    // 5-6: main layer 0
    gemm_inproj<150><<<gg, bb, 0, stream>>>(xr, W0, b0i, b0h, xgB);
    lstm_rec<1><<<256, 512, 0, stream>>>(xgB, nullptr, U0, nullptr,
                                         nullptr, nullptr, nullptr, nullptr,
                                         h0, nullptr);
    // 7-8: main layer 1
    gemm_inproj<100><<<gg, bb, 0, stream>>>(h0, W1, b1i, b1h, xgB);
    lstm_rec<1><<<256, 512, 0, stream>>>(xgB, nullptr, U1, nullptr,
                                         nullptr, nullptr, nullptr, nullptr,
                                         h1, nullptr);
    // 9-10: main layer 2 + fc + mean + softmax
    gemm_inproj<100><<<gg, bb, 0, stream>>>(h1, W2, b2i, b2h, xgB);
    lstm_rec<2><<<256, 512, 0, stream>>>(xgB, nullptr, U2, nullptr,
                                         fcW, fcb, nullptr, nullptr,
                                         out, nullptr);
}

// Round 4
// 2724.849 us; speedup vs baseline: 1.1984x; 1.1984x over previous
//
#include <hip/hip_runtime.h>
#include <cstddef>

#define NB   256   // batch
#define TT   300   // timesteps
#define SS   150   // input feature dim
#define HH   100   // hidden
#define G4   400   // 4*H gates
#define NCLS 60

__device__ __forceinline__ float sigf(float x) {
    float e = __expf(-x);
    return 1.f / (1.f + e);
}
__device__ __forceinline__ float tanh_fast(float x) {
    float e = __expf(2.f * x);
    return 1.f - 2.f / (e + 1.f);
}
__device__ __forceinline__ float rlane(float v, int l) {
    return __int_as_float(__builtin_amdgcn_readlane(__float_as_int(v), l));
}

// ---------------------------------------------------------------------------
// GEMM: C[M x 400] = A[M x K] * W[400 x K]^T + (bih + bhh)   (unchanged)
// ---------------------------------------------------------------------------
template<int K>
__global__ __launch_bounds__(256, 2) void gemm_inproj(
    const float* __restrict__ A, const float* __restrict__ W,
    const float* __restrict__ bih, const float* __restrict__ bhh,
    float* __restrict__ C)
{
    __shared__ float As[K][64];
    __shared__ float Bs[K][64];
    const int m0 = blockIdx.x * 64;
    const int n0 = blockIdx.y * 64;
    const int tid = threadIdx.x;
    const int r = tid & 63;
    constexpr int K2 = K / 2;

    for (int i = tid; i < 64 * K2; i += 256) {
        int c2 = i >> 6;
        float2 v = *(const float2*)(A + (size_t)(m0 + r) * K + 2 * c2);
        As[2 * c2][r] = v.x;
        As[2 * c2 + 1][r] = v.y;
    }
    {
        int g = n0 + r;
        if (g < G4) {
            for (int i = tid; i < 64 * K2; i += 256) {
                int c2 = i >> 6;
                float2 v = *(const float2*)(W + (size_t)g * K + 2 * c2);
                Bs[2 * c2][r] = v.x;
                Bs[2 * c2 + 1][r] = v.y;
            }
        } else {
            for (int i = tid; i < 64 * K2; i += 256) {
                int c2 = i >> 6;
                Bs[2 * c2][r] = 0.f;
                Bs[2 * c2 + 1][r] = 0.f;
            }
        }
    }
    __syncthreads();

    const int tx = tid & 15, ty = tid >> 4;
    float acc[4][4] = {};
#pragma unroll 10
    for (int k = 0; k < K; ++k) {
        float4 a = *(const float4*)&As[k][ty * 4];
        float4 b = *(const float4*)&Bs[k][tx * 4];
        acc[0][0] += a.x * b.x; acc[0][1] += a.x * b.y; acc[0][2] += a.x * b.z; acc[0][3] += a.x * b.w;
        acc[1][0] += a.y * b.x; acc[1][1] += a.y * b.y; acc[1][2] += a.y * b.z; acc[1][3] += a.y * b.w;
        acc[2][0] += a.z * b.x; acc[2][1] += a.z * b.y; acc[2][2] += a.z * b.z; acc[2][3] += a.z * b.w;
        acc[3][0] += a.w * b.x; acc[3][1] += a.w * b.y; acc[3][2] += a.w * b.z; acc[3][3] += a.w * b.w;
    }

    const int g0 = n0 + tx * 4;
    if (g0 + 3 < G4) {
        float b0 = bih[g0] + bhh[g0];
        float b1 = bih[g0 + 1] + bhh[g0 + 1];
        float b2 = bih[g0 + 2] + bhh[g0 + 2];
        float b3 = bih[g0 + 3] + bhh[g0 + 3];
#pragma unroll
        for (int i = 0; i < 4; ++i) {
            float4 o;
            o.x = acc[i][0] + b0; o.y = acc[i][1] + b1;
            o.z = acc[i][2] + b2; o.w = acc[i][3] + b3;
            *(float4*)(C + (size_t)(m0 + ty * 4 + i) * G4 + g0) = o;
        }
    }
}

// ---------------------------------------------------------------------------
// LSTM recurrence, readlane-broadcast design. One block (896 thr) per seq.
// 800 workers: row g = (wave%7)*64+lane (g<400 active), k-half per wave:
//   waves 0-6: k in [0,52); waves 7-13: k in [52,100).
// Each worker holds 52 (or 48) Whh weights in VGPRs (~80 total regs -> fits
// the 128-reg/4-wave budget naturally; no spill, no hints).
// Per step: wave loads its h-slice into ONE VGPR (1 ds_read_b32), broadcasts
// each h_k via v_readlane into the FMA. Partials combine via part_lds[800].
// MODE 0: rot+tr fused (512 blocks). MODE 1: write h seq. MODE 2: mean+fc+sm.
// ---------------------------------------------------------------------------
template<int MODE>
__global__ __launch_bounds__(896, 1) void lstm_rec(
    const float* __restrict__ xgA, const float* __restrict__ xgB,
    const float* __restrict__ WhhA, const float* __restrict__ WhhB,
    const float* __restrict__ fwA, const float* __restrict__ fbA,
    const float* __restrict__ fwB, const float* __restrict__ fbB,
    float* __restrict__ oA, float* __restrict__ oB)
{
    constexpr int FSZ = (MODE == 2) ? (NCLS * HH + NCLS) : (3 * HH + 4);
    __shared__ float h_lds[128];      // [100..128) stays 0 (padding for half1 slice reads)
    __shared__ float part_lds[800];   // [half][row]
    __shared__ float fcw[FSZ];

    const int tid = threadIdx.x;
    int n = blockIdx.x;
    const float* xg = xgA;
    const float* whh = WhhA;
    const float* fw = fwA;
    const float* fb = fbA;
    float* op = oA;
    if (MODE == 0 && blockIdx.x >= NB) {
        n = blockIdx.x - NB;
        xg = xgB; whh = WhhB; fw = fwB; fb = fbB; op = oB;
    }

    const int wave = tid >> 6, lane = tid & 63;
    const int halfk = (wave >= 7) ? 1 : 0;
    const int g = (halfk ? wave - 7 : wave) * 64 + lane;  // gate row (may be >=400)
    const bool act = (g < G4);
    const int k0 = halfk ? 52 : 0;

    // --- load this thread's weight slice: Whh[g, k0 .. k0+51] (48 for half1)
    float4 wq[13];
    if (act) {
        const float4* wr = (const float4*)(whh + (size_t)g * HH + k0);
        const int cnt = halfk ? 12 : 13;
#pragma unroll 13
        for (int j = 0; j < 13; ++j)
            if (j < cnt) wq[j] = wr[j];
    }
    if (halfk) wq[12] = make_float4(0.f, 0.f, 0.f, 0.f);  // zero tail (h pad is 0)

    if (tid < 128) h_lds[tid] = 0.f;   // h init + zero padding
    if (MODE == 0) {
        for (int i = tid; i < 3 * HH; i += 896) fcw[i] = fw[i];
        if (tid < 3) fcw[3 * HH + tid] = fb[tid];
    }
    if (MODE == 2) {
        for (int i = tid; i < NCLS * HH; i += 896) fcw[i] = fw[i];
        if (tid < NCLS) fcw[NCLS * HH + tid] = fb[tid];
    }
    float c = 0.f, hsum = 0.f;
    __syncthreads();

    // xg pipeline (the xg addend is owned by the half-0 worker of each row)
    const bool act0 = act && (halfk == 0);
    const float* xgn = xg + (size_t)n * TT * G4 + g;
    float x0 = 0.f, x1 = 0.f;
    if (act0) { x0 = xgn[0]; x1 = xgn[G4]; }

    for (int t = 0; t < TT; ++t) {
        // wave's h slice: lane l holds h[k0 + l] (pad region is 0)
        float hreg = h_lds[k0 + lane];

        float a0 = act0 ? x0 : 0.f;
        float a1 = 0.f, a2 = 0.f, a3 = 0.f;
        x0 = x1;
        if (act0 && t + 2 < TT) x1 = xgn[(size_t)(t + 2) * G4];

#pragma unroll
        for (int j = 0; j < 13; j += 4) {
            float4 q0 = wq[j];
            a0 += rlane(hreg, 4 * j + 0) * q0.x;
            a0 += rlane(hreg, 4 * j + 1) * q0.y;
            a0 += rlane(hreg, 4 * j + 2) * q0.z;
            a0 += rlane(hreg, 4 * j + 3) * q0.w;
            if (j + 1 < 13) {
                float4 q1 = wq[j + 1];
                a1 += rlane(hreg, 4 * j + 4) * q1.x;
                a1 += rlane(hreg, 4 * j + 5) * q1.y;
                a1 += rlane(hreg, 4 * j + 6) * q1.z;
                a1 += rlane(hreg, 4 * j + 7) * q1.w;
            }
            if (j + 2 < 13) {
                float4 q2 = wq[j + 2];
                a2 += rlane(hreg, 4 * j + 8) * q2.x;
                a2 += rlane(hreg, 4 * j + 9) * q2.y;
                a2 += rlane(hreg, 4 * j + 10) * q2.z;
                a2 += rlane(hreg, 4 * j + 11) * q2.w;
            }
            if (j + 3 < 13) {
                float4 q3 = wq[j + 3];
                a3 += rlane(hreg, 4 * j + 12) * q3.x;
                a3 += rlane(hreg, 4 * j + 13) * q3.y;
                a3 += rlane(hreg, 4 * j + 14) * q3.z;
                a3 += rlane(hreg, 4 * j + 15) * q3.w;
            }
        }
        if (act) part_lds[halfk * G4 + g] = (a0 + a1) + (a2 + a3);
        __syncthreads();

        if (tid < HH) {
            float ig = sigf(part_lds[tid] + part_lds[G4 + tid]);
            float fg = sigf(part_lds[tid + HH] + part_lds[G4 + tid + HH]);
            float gg = tanh_fast(part_lds[tid + 2 * HH] + part_lds[G4 + tid + 2 * HH]);
            float og = sigf(part_lds[tid + 3 * HH] + part_lds[G4 + tid + 3 * HH]);
            c = fg * c + ig * gg;
            float h = og * tanh_fast(c);
            h_lds[tid] = h;
            if (MODE == 1) op[((size_t)n * TT + t) * HH + tid] = h;
            if (MODE == 2) hsum += h;
        }
        __syncthreads();

        if (MODE == 0 && tid < 64) {
            // wave0's fc of h_t; safe: h rewrite needs next barrier which
            // wave0 only reaches after finishing this.
            float p0 = 0.f, p1 = 0.f, p2 = 0.f;
            for (int k = tid; k < HH; k += 64) {
                float hk = h_lds[k];
                p0 += hk * fcw[k];
                p1 += hk * fcw[HH + k];
                p2 += hk * fcw[2 * HH + k];
            }
#pragma unroll
            for (int s = 32; s; s >>= 1) {
                p0 += __shfl_xor(p0, s);
                p1 += __shfl_xor(p1, s);
                p2 += __shfl_xor(p2, s);
            }
            if (tid == 0) {
                size_t o = ((size_t)n * TT + t) * 3;
                op[o] = p0 + fcw[3 * HH];
                op[o + 1] = p1 + fcw[3 * HH + 1];
                op[o + 2] = p2 + fcw[3 * HH + 2];
            }
        }
    }

    if (MODE == 2) {
        if (tid < HH) h_lds[tid] = hsum * (1.f / TT);
        __syncthreads();
        if (tid < 64) {
            float logit = -3.0e38f;
            if (tid < NCLS) {
                float a = fcw[NCLS * HH + tid];
#pragma unroll
                for (int k = 0; k < HH; ++k) a += h_lds[k] * fcw[tid * HH + k];
                logit = a;
            }
            float mx = logit;
#pragma unroll
            for (int s = 32; s; s >>= 1) mx = fmaxf(mx, __shfl_xor(mx, s));
            float e = (tid < NCLS) ? __expf(logit - mx) : 0.f;
            float sum = e;
#pragma unroll
            for (int s = 32; s; s >>= 1) sum += __shfl_xor(sum, s);
            if (tid < NCLS) op[(size_t)n * NCLS + tid] = e / sum;
        }
    }
}

// ---------------------------------------------------------------------------
// Rotation/translation transform (unchanged)
// ---------------------------------------------------------------------------
__global__ __launch_bounds__(256) void transform_pts(
    const float* __restrict__ x, const float* __restrict__ rot,
    const float* __restrict__ tr, float* __restrict__ xr)
{
    const int idx = blockIdx.x * 4 + (threadIdx.x >> 6);
    const int lane = threadIdx.x & 63;
    const float* ang = rot + (size_t)idx * 3;
    float a = ang[0], b = ang[1], cg = ang[2];
    float ca = cosf(a), sa = sinf(a);
    float cb = cosf(b), sb = sinf(b);
    float cc = cosf(cg), sc = sinf(cg);
    float R00 = cc * cb, R01 = cc * sb * sa + sc * ca, R02 = -cc * sb * ca + sc * sa;
    float R10 = -sc * cb, R11 = -sc * sb * sa + cc * ca, R12 = sc * sb * ca + cc * sa;
    float R20 = sb, R21 = -cb * sa, R22 = cb * ca;
    float t0 = tr[(size_t)idx * 3], t1 = tr[(size_t)idx * 3 + 1], t2 = tr[(size_t)idx * 3 + 2];
    if (lane < 50) {
        const float* xp = x + (size_t)idx * SS + lane * 3;
        float p0 = xp[0] - t0, p1 = xp[1] - t1, p2 = xp[2] - t2;
        float* o = xr + (size_t)idx * SS + lane * 3;
        o[0] = R00 * p0 + R01 * p1 + R02 * p2;
        o[1] = R10 * p0 + R11 * p1 + R12 * p2;
        o[2] = R20 * p0 + R21 * p1 + R22 * p2;
    }
}

// ---------------------------------------------------------------------------
extern "C" void kernel_launch(void* const* d_in, const int* in_sizes, int n_in,
                              void* d_out, int out_size, void* d_ws, size_t ws_size,
                              hipStream_t stream)
{
    const float* x       = (const float*)d_in[0];
    const float* rot_Wih = (const float*)d_in[1];
    const float* rot_Whh = (const float*)d_in[2];
    const float* rot_bih = (const float*)d_in[3];
    const float* rot_bhh = (const float*)d_in[4];
    const float* tr_Wih  = (const float*)d_in[5];
    const float* tr_Whh  = (const float*)d_in[6];
    const float* tr_bih  = (const float*)d_in[7];
    const float* tr_bhh  = (const float*)d_in[8];
    const float* rot_fcW = (const float*)d_in[9];
    const float* rot_fcb = (const float*)d_in[10];
    const float* tr_fcW  = (const float*)d_in[11];
    const float* tr_fcb  = (const float*)d_in[12];
    const float* W0 = (const float*)d_in[13];
    const float* U0 = (const float*)d_in[14];
    const float* b0i = (const float*)d_in[15];
    const float* b0h = (const float*)d_in[16];
    const float* W1 = (const float*)d_in[17];
    const float* U1 = (const float*)d_in[18];
    const float* b1i = (const float*)d_in[19];
    const float* b1h = (const float*)d_in[20];
    const float* W2 = (const float*)d_in[21];
    const float* U2 = (const float*)d_in[22];
    const float* b2i = (const float*)d_in[23];
    const float* b2h = (const float*)d_in[24];
    const float* fcW = (const float*)d_in[25];
    const float* fcb = (const float*)d_in[26];
    float* out = (float*)d_out;

    float* ws = (float*)d_ws;
    float* xgA  = ws;
    float* xgB  = ws + 30720000ull;
    float* rotA = ws + 61440000ull;
    float* trO  = ws + 61670400ull;
    float* xr = xgA;
    float* h0 = xgA + 11520000ull;
    float* h1 = xgA + 19200000ull;

    dim3 gg(1200, 7), bb(256);
    gemm_inproj<150><<<gg, bb, 0, stream>>>(x, rot_Wih, rot_bih, rot_bhh, xgA);
    gemm_inproj<150><<<gg, bb, 0, stream>>>(x, tr_Wih, tr_bih, tr_bhh, xgB);
    lstm_rec<0><<<512, 896, 0, stream>>>(xgA, xgB, rot_Whh, tr_Whh,
                                         rot_fcW, rot_fcb, tr_fcW, tr_fcb,
                                         rotA, trO);
    transform_pts<<<19200, 256, 0, stream>>>(x, rotA, trO, xr);
    gemm_inproj<150><<<gg, bb, 0, stream>>>(xr, W0, b0i, b0h, xgB);
    lstm_rec<1><<<256, 896, 0, stream>>>(xgB, nullptr, U0, nullptr,
                                         nullptr, nullptr, nullptr, nullptr,
                                         h0, nullptr);
    gemm_inproj<100><<<gg, bb, 0, stream>>>(h0, W1, b1i, b1h, xgB);
    lstm_rec<1><<<256, 896, 0, stream>>>(xgB, nullptr, U1, nullptr,
                                         nullptr, nullptr, nullptr, nullptr,
                                         h1, nullptr);
    gemm_inproj<100><<<gg, bb, 0, stream>>>(h1, W2, b2i, b2h, xgB);
    lstm_rec<2><<<256, 896, 0, stream>>>(xgB, nullptr, U2, nullptr,
                                         fcW, fcb, nullptr, nullptr,
                                         out, nullptr);
}